// Round 5
// baseline (818.517 us; speedup 1.0000x reference)
//
#include <hip/hip_runtime.h>
#include <hip/hip_bf16.h>

#define T_SEQ 2048
#define NH 32
#define HD 128
#define QKV_N 12288
#define V_OFF 8192

typedef __bf16 bf16;
typedef __attribute__((ext_vector_type(4))) __bf16 bf16x4;
typedef __attribute__((ext_vector_type(8))) __bf16 bf16x8;
typedef __attribute__((ext_vector_type(4))) float f32x4;

#define GLDS16(g, l)                                                        \
  __builtin_amdgcn_global_load_lds(                                         \
      (const __attribute__((address_space(1))) void*)(g),                   \
      (__attribute__((address_space(3))) void*)(l), 16, 0, 0)

// 8-element load -> bf16x8, converting if the source is f32
__device__ inline bf16x8 load8(const bf16* p) { return *(const bf16x8*)p; }
__device__ inline bf16x8 load8(const float* p) {
    f32x4 a = *(const f32x4*)p;
    f32x4 b = *(const f32x4*)(p + 4);
    bf16x8 r;
    r[0] = (bf16)a[0]; r[1] = (bf16)a[1]; r[2] = (bf16)a[2]; r[3] = (bf16)a[3];
    r[4] = (bf16)b[0]; r[5] = (bf16)b[1]; r[6] = (bf16)b[2]; r[7] = (bf16)b[3];
    return r;
}

// ---------------- f32 -> bf16 bulk convert ---------------------------------
__global__ __launch_bounds__(256)
void f32_to_bf16(const float* __restrict__ in, bf16* __restrict__ out, int n8)
{
    for (int i = blockIdx.x * 256 + threadIdx.x; i < n8; i += gridDim.x * 256)
        *(bf16x8*)(out + (size_t)i * 8) = load8(in + (size_t)i * 8);
}

// ===========================================================================
// 128x128-tile CO-RESIDENT GEMM (C = A*B^T + bias), bf16.
//   Round-4 post-mortem: 1 block/CU with barrier-locked waves serializes the
//   LDS pipe and the matrix pipe (measured 1567 cyc/K-tile = 621 MFMA + 960
//   LDS, MfmaUtil 35%).  Fix is TLP, not choreography: small blocks, several
//   co-resident per CU, phase-skewed by independence (m114 mechanism).
//   4 waves (2Mx2N, wave 64x64), BK=32, dbuf LDS = 32 KiB, ~115 VGPR,
//   __launch_bounds__(256,3) -> 3 blocks/CU (12 waves).  QKV grid 1536
//   blocks = continuous 6-deep queue per CU; O grid 512 = 2x256 exact.
//   Per iter: {8 ds_read | 4 GLDS stage(kt+1)} -> setprio 16-MFMA ->
//   vmcnt(0) (stage had a full iter in flight; landed) -> s_barrier.
//   WAR: slot (kt+1)&1's last readers (iter kt-1) drained their lgkm before
//   their MFMA, published by the end-of-(kt-1) barrier which precedes this
//   stage.  RAW: vmcnt(0)+barrier at end of kt publishes stage(kt+1).
//   Swizzle (verified 0 conflicts, rounds 1-4): byte ^ ((byte>>3)&0x70);
//   GLDS dest linear, global source pre-swizzled, reads XOR'd (same involution).
// ===========================================================================
template <typename TO>
__global__ __launch_bounds__(256, 3)
void gemm_bt_cr(const bf16* __restrict__ A, int lda,
                const bf16* __restrict__ B,
                const float* __restrict__ bias,
                TO* __restrict__ C, int ldc,
                int mTiles, int colPerXcd, int K)
{
    __shared__ char lds[32768];          // A: 2x8K at [0,16384); B: 2x8K at [16384,32768)

    const int tid  = threadIdx.x;
    const int wave = tid >> 6, lane = tid & 63;
    const int quad = lane >> 4, l16 = lane & 15;
    const int wm = wave >> 1, wn = wave & 1;      // 2M x 2N wave grid

    const int b   = blockIdx.x;
    const int xcd = b & 7, i = b >> 3;
    const int rowBase = (i % mTiles) * 128;
    const int colBase = (xcd * colPerXcd + i / mTiles) * 128;
    const int nK = K >> 5;                        // BK=32 K-tiles

    // ---- staging sources: linear LDS chunk -> pre-swizzled global address
    const bf16* gA[2];
    const bf16* gB[2];
#pragma unroll
    for (int j = 0; j < 2; ++j) {
        int d = (j * 256 + tid) * 16;             // linear byte in 8K slot
        int s = d ^ ((d >> 3) & 0x70);            // semantic byte (involution)
        int row = s >> 6, ke = (s & 63) >> 1;     // 64-B rows
        gA[j] = A + (size_t)(rowBase + row) * lda + ke;
        gB[j] = B + (size_t)(colBase + row) * K + ke;
    }

    auto stage = [&](int kt) {
        const int sl = kt & 1;
        const int ko = kt * 32;
#pragma unroll
        for (int j = 0; j < 2; ++j) {
            GLDS16(gA[j] + ko, lds + sl * 8192 + j * 4096 + wave * 1024);
            GLDS16(gB[j] + ko, lds + 16384 + sl * 8192 + j * 4096 + wave * 1024);
        }
    };

    // ---- ds_read fragment byte offsets (swizzled)
    int offA[4], offB[4];
#pragma unroll
    for (int mi = 0; mi < 4; ++mi) {
        int a = (wm * 64 + mi * 16 + l16) * 64 + quad * 16;
        offA[mi] = a ^ ((a >> 3) & 0x70);
    }
#pragma unroll
    for (int ni = 0; ni < 4; ++ni) {
        int a = (wn * 64 + ni * 16 + l16) * 64 + quad * 16;
        offB[ni] = a ^ ((a >> 3) & 0x70);
    }

    f32x4 acc[4][4] = {};

    // ---- prologue
    stage(0);
    asm volatile("s_waitcnt vmcnt(0)" ::: "memory");
    __builtin_amdgcn_s_barrier();

#pragma unroll 2
    for (int kt = 0; kt < nK; ++kt) {
        const char* sA = lds + (kt & 1) * 8192;
        const char* sB = lds + 16384 + (kt & 1) * 8192;
        bf16x8 af[4], bfr[4];
#pragma unroll
        for (int mi = 0; mi < 4; ++mi) af[mi]  = *(const bf16x8*)(sA + offA[mi]);
#pragma unroll
        for (int ni = 0; ni < 4; ++ni) bfr[ni] = *(const bf16x8*)(sB + offB[ni]);
        if (kt + 1 < nK) stage(kt + 1);           // in flight across the MFMAs
        __builtin_amdgcn_sched_barrier(0);
        __builtin_amdgcn_s_setprio(1);
#pragma unroll
        for (int mi = 0; mi < 4; ++mi)
#pragma unroll
            for (int ni = 0; ni < 4; ++ni)
                acc[mi][ni] = __builtin_amdgcn_mfma_f32_16x16x32_bf16(
                    af[mi], bfr[ni], acc[mi][ni], 0, 0, 0);
        __builtin_amdgcn_s_setprio(0);
        __builtin_amdgcn_sched_barrier(0);
        if (kt + 1 < nK) {
            asm volatile("s_waitcnt vmcnt(0)" ::: "memory");
            __builtin_amdgcn_s_barrier();
        }
    }

    // ---- epilogue
#pragma unroll
    for (int ni = 0; ni < 4; ++ni) {
        int col = colBase + wn * 64 + ni * 16 + l16;
        float bv = bias ? bias[col] : 0.0f;
#pragma unroll
        for (int mi = 0; mi < 4; ++mi) {
            int row0 = rowBase + wm * 64 + mi * 16 + quad * 4;
#pragma unroll
            for (int r = 0; r < 4; ++r)
                C[(size_t)(row0 + r) * ldc + col] = (TO)(acc[mi][ni][r] + bv);
        }
    }
}

#define BM 128
#define BN 128
#define BK 32

// ---------------- fallback GEMM (mixed dtype, register staging) ------------
template <typename TA, typename TB, typename TO>
__global__ __launch_bounds__(256, 2)
void gemm_bt_bias(const TA* __restrict__ A, int lda,
                  const TB* __restrict__ B,
                  const float* __restrict__ bias,
                  TO* __restrict__ C, int ldc,
                  int M, int N, int K)
{
    __shared__ bf16 sA[BM * BK];
    __shared__ bf16 sB[BN * BK];
    const int tid  = threadIdx.x;
    const int wave = tid >> 6, lane = tid & 63;
    const int quad = lane >> 4, l16 = lane & 15;
    const int wm = wave >> 1, wn = wave & 1;
    const int rowBase = blockIdx.x * BM;
    const int colBase = blockIdx.y * BN;

    int c0 = wave * 128 + lane;
    int rowA0 = c0 >> 2, kgA0 = c0 & 3;
    int rowA1 = (c0 + 64) >> 2, kgA1 = (c0 + 64) & 3;

    f32x4 acc[4][4] = {};

    for (int k0 = 0; k0 < K; k0 += BK) {
        bf16x8 ra0 = load8(A + (size_t)(rowBase + rowA0) * lda + k0 + kgA0 * 8);
        bf16x8 ra1 = load8(A + (size_t)(rowBase + rowA1) * lda + k0 + kgA1 * 8);
        bf16x8 rb0 = load8(B + (size_t)(colBase + rowA0) * K + k0 + kgA0 * 8);
        bf16x8 rb1 = load8(B + (size_t)(colBase + rowA1) * K + k0 + kgA1 * 8);
        __syncthreads();
        *(bf16x8*)(sA + rowA0 * BK + kgA0 * 8) = ra0;
        *(bf16x8*)(sA + rowA1 * BK + kgA1 * 8) = ra1;
        *(bf16x8*)(sB + rowA0 * BK + kgA0 * 8) = rb0;
        *(bf16x8*)(sB + rowA1 * BK + kgA1 * 8) = rb1;
        __syncthreads();

        bf16x8 af[4], bfr[4];
        for (int mi = 0; mi < 4; ++mi)
            af[mi] = *(const bf16x8*)(sA + (wm * 64 + mi * 16 + l16) * BK + quad * 8);
        for (int ni = 0; ni < 4; ++ni)
            bfr[ni] = *(const bf16x8*)(sB + (wn * 64 + ni * 16 + l16) * BK + quad * 8);
        for (int mi = 0; mi < 4; ++mi)
            for (int ni = 0; ni < 4; ++ni)
                acc[mi][ni] = __builtin_amdgcn_mfma_f32_16x16x32_bf16(
                    af[mi], bfr[ni], acc[mi][ni], 0, 0, 0);
    }

    for (int ni = 0; ni < 4; ++ni) {
        int col = colBase + wn * 64 + ni * 16 + l16;
        float bv = bias ? bias[col] : 0.0f;
        for (int mi = 0; mi < 4; ++mi) {
            int row0 = rowBase + wm * 64 + mi * 16 + quad * 4;
            for (int r = 0; r < 4; ++r)
                C[(size_t)(row0 + r) * ldc + col] = (TO)(acc[mi][ni][r] + bv);
        }
    }
}

// ---------------- RMSNorm (over full 4096) + RoPE, IN PLACE ----------------
__global__ __launch_bounds__(256)
void rmsnorm_rope(bf16* __restrict__ qkv, const float* __restrict__ qw,
                  const float* __restrict__ kw, const int* __restrict__ pos)
{
    const int t   = blockIdx.x;
    const int sel = blockIdx.y;
    bf16* x = qkv + (size_t)t * QKV_N + sel * 4096;
    const float* w = sel ? kw : qw;
    const int tid = threadIdx.x;

    float ss = 0.f;
    {
        int i0 = tid * 16;
        bf16x8 a = *(const bf16x8*)(x + i0);
        bf16x8 b = *(const bf16x8*)(x + i0 + 8);
        for (int j = 0; j < 8; ++j) { float fa = (float)a[j]; ss += fa * fa; }
        for (int j = 0; j < 8; ++j) { float fb = (float)b[j]; ss += fb * fb; }
    }
    for (int off = 1; off < 64; off <<= 1) ss += __shfl_xor(ss, off, 64);
    __shared__ float red[4];
    if ((tid & 63) == 0) red[tid >> 6] = ss;
    __syncthreads();
    float tot = red[0] + red[1] + red[2] + red[3];
    float rstd = rsqrtf(tot * (1.0f / 4096.0f) + 1e-5f);

    float fp = (float)pos[t];
    for (int i = tid; i < 2048; i += 256) {
        int h = i >> 6;
        int d = i & 63;
        int base = h * 128 + d;
        float x1 = (float)x[base]      * rstd * w[base];
        float x2 = (float)x[base + 64] * rstd * w[base + 64];
        float ang = fp * exp2f(-(float)d * 0.31143075889569023f);
        float s, c;
        sincosf(ang, &s, &c);
        x[base]      = (bf16)(x1 * c - x2 * s);
        x[base + 64] = (bf16)(x2 * c + x1 * s);
    }
}

// ---------------- V transpose ----------------------------------------------
__global__ __launch_bounds__(256)
void v_transpose(const bf16* __restrict__ qkv, bf16* __restrict__ vt)
{
    __shared__ bf16 tile[64][65];
    int t0 = blockIdx.x * 64, d0 = blockIdx.y * 64, h = blockIdx.z;
    int x = threadIdx.x & 63, y4 = threadIdx.x >> 6;
    for (int yy = y4; yy < 64; yy += 4)
        tile[yy][x] = qkv[(size_t)(t0 + yy) * QKV_N + V_OFF + h * HD + d0 + x];
    __syncthreads();
    for (int yy = y4; yy < 64; yy += 4)
        vt[(size_t)(h * HD + d0 + yy) * T_SEQ + t0 + x] = tile[x][yy];
}

// ---------------- Flash attention (causal) ---------------------------------
#define SKP 136
#define SVP 72
#define PBP 72

__global__ __launch_bounds__(256, 2)
void flash_attn(bf16* qkv, const bf16* vt)
{
    __shared__ bf16 sK[64 * SKP];
    __shared__ bf16 sV[128 * SVP];
    __shared__ bf16 pbuf[4 * 16 * PBP];

    const int tid  = threadIdx.x;
    const int wave = tid >> 6, lane = tid & 63;
    const int quad = lane >> 4, l16 = lane & 15;
    const int h    = blockIdx.y;

    const float sc = 0.08838834764831845f * 1.4426950408889634f;  // scale*log2e
    bf16* pb = pbuf + wave * 16 * PBP;

    for (int half = 0; half < 2; ++half) {
        const int blk  = half ? (31 - (int)blockIdx.x) : (int)blockIdx.x;
        const int q0w  = blk * 64 + wave * 16;
        const int kend = blk * 64;
        const int qln  = q0w + l16;

        bf16x8 qf[4];
        {
            const bf16* qrow = qkv + (size_t)qln * QKV_N + h * HD;
            for (int c = 0; c < 4; ++c)
                qf[c] = *(const bf16x8*)(qrow + c * 32 + quad * 8);
        }

        f32x4 oacc[8] = {};
        float m2 = -1e30f, lsum = 0.f;

        for (int kb = 0; kb <= kend; kb += 64) {
            __syncthreads();
            for (int j = 0; j < 4; ++j) {
                int c = tid + j * 256;
                int r = c >> 4, off = (c & 15) * 8;
                bf16x8 v = *(const bf16x8*)(qkv + (size_t)(kb + r) * QKV_N + 4096 + h * HD + off);
                *(bf16x8*)(sK + r * SKP + off) = v;
            }
            for (int j = 0; j < 4; ++j) {
                int c = tid + j * 256;
                int d = c >> 3, off = (c & 7) * 8;
                bf16x8 v = *(const bf16x8*)(vt + (size_t)(h * HD + d) * T_SEQ + kb + off);
                *(bf16x8*)(sV + d * SVP + off) = v;
            }
            __syncthreads();

            const int stmax = (kb == kend) ? (wave + 1) : 4;

            f32x4 s[4] = {};
            for (int st = 0; st < 4; ++st) {
                if (st >= stmax) break;
                const bf16* kbase = sK + (st * 16 + l16) * SKP + quad * 8;
                for (int c = 0; c < 4; ++c) {
                    bf16x8 kf = *(const bf16x8*)(kbase + c * 32);
                    s[st] = __builtin_amdgcn_mfma_f32_16x16x32_bf16(kf, qf[c], s[st], 0, 0, 0);
                }
            }
            for (int st = 0; st < 4; ++st) {
                int k0r = kb + st * 16 + quad * 4;
                for (int r = 0; r < 4; ++r) {
                    float v = s[st][r] * sc;
                    s[st][r] = (k0r + r <= qln) ? v : -1e30f;
                }
            }
            float mx = -1e30f;
            for (int st = 0; st < 4; ++st)
                for (int r = 0; r < 4; ++r) mx = fmaxf(mx, s[st][r]);
            mx = fmaxf(mx, __shfl_xor(mx, 16, 64));
            mx = fmaxf(mx, __shfl_xor(mx, 32, 64));
            float mnew  = fmaxf(m2, mx);
            float alpha = exp2f(m2 - mnew);
            float ps = 0.f;
            for (int st = 0; st < 4; ++st)
                for (int r = 0; r < 4; ++r) {
                    float p = exp2f(s[st][r] - mnew);
                    s[st][r] = p;
                    ps += p;
                }
            ps += __shfl_xor(ps, 16, 64);
            ps += __shfl_xor(ps, 32, 64);
            lsum = lsum * alpha + ps;
            m2 = mnew;

            float ar[4];
            for (int r = 0; r < 4; ++r) ar[r] = __shfl(alpha, quad * 4 + r, 64);
            for (int c = 0; c < 8; ++c)
                for (int r = 0; r < 4; ++r) oacc[c][r] *= ar[r];

            for (int st = 0; st < 4; ++st) {
                bf16x4 pw;
                for (int r = 0; r < 4; ++r) pw[r] = (bf16)s[st][r];
                *(bf16x4*)(pb + l16 * PBP + st * 16 + quad * 4) = pw;
            }
            __builtin_amdgcn_s_waitcnt(0xC07F);  // lgkmcnt(0)
            for (int ph = 0; ph < 2; ++ph) {
                bf16x8 pf = *(const bf16x8*)(pb + l16 * PBP + ph * 32 + quad * 8);
                for (int c = 0; c < 8; ++c) {
                    bf16x8 vf = *(const bf16x8*)(sV + (c * 16 + l16) * SVP + ph * 32 + quad * 8);
                    oacc[c] = __builtin_amdgcn_mfma_f32_16x16x32_bf16(pf, vf, oacc[c], 0, 0, 0);
                }
            }
        }

        float lr[4];
        for (int r = 0; r < 4; ++r) lr[r] = __shfl(lsum, quad * 4 + r, 64);
        for (int r = 0; r < 4; ++r) {
            float inv = 1.0f / lr[r];
            int t = q0w + quad * 4 + r;
            for (int c = 0; c < 8; ++c)
                qkv[(size_t)t * QKV_N + V_OFF + h * HD + c * 16 + l16] =
                    (bf16)(oacc[c][r] * inv);
        }
    }
}

extern "C" void kernel_launch(void* const* d_in, const int* in_sizes, int n_in,
                              void* d_out, int out_size, void* d_ws, size_t ws_size,
                              hipStream_t stream)
{
    const float* hidden   = (const float*)d_in[0];
    const int*   pos      = (const int*)d_in[1];
    const float* w_qkv    = (const float*)d_in[2];
    const float* b_qkv    = (const float*)d_in[3];
    const float* q_norm_w = (const float*)d_in[4];
    const float* k_norm_w = (const float*)d_in[5];
    const float* w_o      = (const float*)d_in[6];
    float* out = (float*)d_out;

    bf16* qkv = (bf16*)d_ws;                         //  50.33 MB
    bf16* vt  = qkv + (size_t)T_SEQ * QKV_N;         //  16.78 MB
    bf16* wqb = vt  + (size_t)4096 * T_SEQ;          // 100.66 MB
    bf16* wob = wqb + (size_t)QKV_N * 4096;          //  33.55 MB
    bf16* hib = wob + (size_t)4096 * 4096;           //  16.78 MB
    const size_t need = ((size_t)T_SEQ * QKV_N + (size_t)4096 * T_SEQ +
                         (size_t)QKV_N * 4096 + (size_t)4096 * 4096 +
                         (size_t)T_SEQ * 4096) * 2;

    if (ws_size >= need) {
        f32_to_bf16<<<2048, 256, 0, stream>>>(hidden, hib, T_SEQ * 4096 / 8);
        f32_to_bf16<<<8192, 256, 0, stream>>>(w_qkv, wqb, QKV_N * 4096 / 8);
        f32_to_bf16<<<4096, 256, 0, stream>>>(w_o, wob, 4096 * 4096 / 8);

        // QKV GEMM: 2048x12288x4096; 128x128 tiles -> 16x96 = 1536 blocks,
        // 3 co-resident blocks/CU (6-deep queue, no quantization tail)
        gemm_bt_cr<bf16><<<1536, 256, 0, stream>>>(
            hib, 4096, wqb, b_qkv, qkv, QKV_N, 16, 12, 4096);
        rmsnorm_rope<<<dim3(T_SEQ, 2), 256, 0, stream>>>(qkv, q_norm_w, k_norm_w, pos);
        v_transpose<<<dim3(T_SEQ / 64, 2, NH), 256, 0, stream>>>(qkv, vt);
        flash_attn<<<dim3(T_SEQ / 128, NH), 256, 0, stream>>>(qkv, vt);
        // O GEMM: 2048x4096x4096; 128x128 tiles -> 16x32 = 512 = 2x256 exact
        gemm_bt_cr<float><<<512, 256, 0, stream>>>(
            qkv + V_OFF, QKV_N, wob, nullptr, out, 4096, 16, 4, 4096);
    } else {
        gemm_bt_bias<float, float, bf16><<<dim3(T_SEQ / BM, QKV_N / BN), 256, 0, stream>>>(
            hidden, 4096, w_qkv, b_qkv, qkv, QKV_N, T_SEQ, QKV_N, 4096);
        rmsnorm_rope<<<dim3(T_SEQ, 2), 256, 0, stream>>>(qkv, q_norm_w, k_norm_w, pos);
        v_transpose<<<dim3(T_SEQ / 64, 2, NH), 256, 0, stream>>>(qkv, vt);
        flash_attn<<<dim3(T_SEQ / 128, NH), 256, 0, stream>>>(qkv, vt);
        gemm_bt_bias<bf16, float, float><<<dim3(T_SEQ / BM, 4096 / BN), 256, 0, stream>>>(
            qkv + V_OFF, QKV_N, w_o, nullptr, out, 4096, T_SEQ, 4096, 4096);
    }
}

// Round 6
// 796.567 us; speedup vs baseline: 1.0276x; 1.0276x over previous
//
#include <hip/hip_runtime.h>
#include <hip/hip_bf16.h>

#define T_SEQ 2048
#define NH 32
#define HD 128
#define QKV_N 12288
#define V_OFF 8192

typedef __bf16 bf16;
typedef __attribute__((ext_vector_type(4))) __bf16 bf16x4;
typedef __attribute__((ext_vector_type(8))) __bf16 bf16x8;
typedef __attribute__((ext_vector_type(4))) float f32x4;

#define GLDS16(g, l)                                                        \
  __builtin_amdgcn_global_load_lds(                                         \
      (const __attribute__((address_space(1))) void*)(g),                   \
      (__attribute__((address_space(3))) void*)(l), 16, 0, 0)

// 8-element load -> bf16x8, converting if the source is f32
__device__ inline bf16x8 load8(const bf16* p) { return *(const bf16x8*)p; }
__device__ inline bf16x8 load8(const float* p) {
    f32x4 a = *(const f32x4*)p;
    f32x4 b = *(const f32x4*)(p + 4);
    bf16x8 r;
    r[0] = (bf16)a[0]; r[1] = (bf16)a[1]; r[2] = (bf16)a[2]; r[3] = (bf16)a[3];
    r[4] = (bf16)b[0]; r[5] = (bf16)b[1]; r[6] = (bf16)b[2]; r[7] = (bf16)b[3];
    return r;
}

// ---------------- f32 -> bf16 bulk convert ---------------------------------
__global__ __launch_bounds__(256)
void f32_to_bf16(const float* __restrict__ in, bf16* __restrict__ out, int n8)
{
    for (int i = blockIdx.x * 256 + threadIdx.x; i < n8; i += gridDim.x * 256)
        *(bf16x8*)(out + (size_t)i * 8) = load8(in + (size_t)i * 8);
}

// ===========================================================================
// 256x128-tile one-phase-per-K-tile GEMM (C = A*B^T + bias), bf16.
//   Round-4 measured-best GEMM (251 us QKV) -- restored verbatim.
//   8 waves (4Mx2N), wave tile 64x64, BK=32, 4-slot LDS ring (96 KiB),
//   counted vmcnt, single barrier per K-tile, verified swizzle (0 conflicts).
//   QKV grid 8x96=768 (3 exact rounds); O grid 8x32=256 (1 exact round).
// ===========================================================================
template <typename TO>
__global__ __launch_bounds__(512, 2)
void gemm_bt_p1(const bf16* __restrict__ A, int lda,
                const bf16* __restrict__ B,
                const float* __restrict__ bias,
                TO* __restrict__ C, int ldc,
                int mTiles, int colPerXcd, int K)
{
    __shared__ char lds[98304];          // A: [0,65536) 4x16KB ; B: [65536,98304) 4x8KB
    char* ldsA = lds;
    char* ldsB = lds + 65536;

    const int tid  = threadIdx.x;
    const int wave = tid >> 6, lane = tid & 63;
    const int quad = lane >> 4, l16 = lane & 15;
    const int wm = wave >> 1, wn = wave & 1;      // 4M x 2N wave grid

    const int b   = blockIdx.x;
    const int xcd = b & 7, i = b >> 3;
    const int rowBase = (i % mTiles) * 256;
    const int colBase = (xcd * colPerXcd + i / mTiles) * 128;
    const int nK = K >> 5;                        // BK=32 K-tiles

    // ---- staging sources: linear LDS chunk -> pre-swizzled global address
    const bf16* gA0; const bf16* gA1; const bf16* gB0;
    {
        int d0 = tid * 16;                        // A chunk 0 (16KB slot)
        int s0 = d0 ^ ((d0 >> 3) & 0x70);
        gA0 = A + (size_t)(rowBase + (s0 >> 6)) * lda + ((s0 & 63) >> 1);
        int d1 = (512 + tid) * 16;                // A chunk 1
        int s1 = d1 ^ ((d1 >> 3) & 0x70);
        gA1 = A + (size_t)(rowBase + (s1 >> 6)) * lda + ((s1 & 63) >> 1);
        int d2 = tid * 16;                        // B chunk (8KB slot)
        int s2 = d2 ^ ((d2 >> 3) & 0x70);
        gB0 = B + (size_t)(colBase + (s2 >> 6)) * K + ((s2 & 63) >> 1);
    }

    auto stage = [&](int kt) {
        const int sl = kt & 3;
        const int ko = kt * 32;
        GLDS16(gA0 + ko, ldsA + sl * 16384 + wave * 1024);
        GLDS16(gA1 + ko, ldsA + sl * 16384 + 8192 + wave * 1024);
        GLDS16(gB0 + ko, ldsB + sl * 8192 + wave * 1024);
    };

    // ---- ds_read fragment byte offsets (swizzled)
    int offA[4], offB[4];
#pragma unroll
    for (int mi = 0; mi < 4; ++mi) {
        int a = (wm * 64 + mi * 16 + l16) * 64 + quad * 16;
        offA[mi] = a ^ ((a >> 3) & 0x70);
    }
#pragma unroll
    for (int ni = 0; ni < 4; ++ni) {
        int a = (wn * 64 + ni * 16 + l16) * 64 + quad * 16;
        offB[ni] = a ^ ((a >> 3) & 0x70);
    }

    f32x4 acc[4][4] = {};

    // ---- prologue: 3 K-tiles in flight (9 VMEM/wave), tile 0 landed
    stage(0); stage(1); stage(2);
    asm volatile("s_waitcnt vmcnt(6)" ::: "memory");
    __builtin_amdgcn_s_barrier();

#pragma unroll 4
    for (int kt = 0; kt < nK; ++kt) {
        const char* sA = ldsA + (kt & 3) * 16384;
        const char* sB = ldsB + (kt & 3) * 8192;
        bf16x8 af[4], bfr[4];
#pragma unroll
        for (int mi = 0; mi < 4; ++mi) af[mi]  = *(const bf16x8*)(sA + offA[mi]);
#pragma unroll
        for (int ni = 0; ni < 4; ++ni) bfr[ni] = *(const bf16x8*)(sB + offB[ni]);
        if (kt + 3 < nK) stage(kt + 3);
        __builtin_amdgcn_sched_barrier(0);        // reads+stage issued first
        __builtin_amdgcn_s_setprio(1);
#pragma unroll
        for (int mi = 0; mi < 4; ++mi)
#pragma unroll
            for (int ni = 0; ni < 4; ++ni)
                acc[mi][ni] = __builtin_amdgcn_mfma_f32_16x16x32_bf16(
                    af[mi], bfr[ni], acc[mi][ni], 0, 0, 0);
        __builtin_amdgcn_s_setprio(0);
        __builtin_amdgcn_sched_barrier(0);
        // counted drain: oldest outstanding tile (kt+1) landed; never 0 mid-loop
        if (kt + 3 < nK) {
            asm volatile("s_waitcnt vmcnt(6)" ::: "memory");
            __builtin_amdgcn_s_barrier();
        } else if (kt + 2 < nK) {
            asm volatile("s_waitcnt vmcnt(3)" ::: "memory");
            __builtin_amdgcn_s_barrier();
        } else if (kt + 1 < nK) {
            asm volatile("s_waitcnt vmcnt(0)" ::: "memory");
            __builtin_amdgcn_s_barrier();
        }
    }

    // ---- epilogue
#pragma unroll
    for (int ni = 0; ni < 4; ++ni) {
        int col = colBase + wn * 64 + ni * 16 + l16;
        float bv = bias ? bias[col] : 0.0f;
#pragma unroll
        for (int mi = 0; mi < 4; ++mi) {
            int row0 = rowBase + wm * 64 + mi * 16 + quad * 4;
#pragma unroll
            for (int r = 0; r < 4; ++r)
                C[(size_t)(row0 + r) * ldc + col] = (TO)(acc[mi][ni][r] + bv);
        }
    }
}

#define BM 128
#define BN 128
#define BK 32

// ---------------- fallback GEMM (mixed dtype, register staging) ------------
template <typename TA, typename TB, typename TO>
__global__ __launch_bounds__(256, 2)
void gemm_bt_bias(const TA* __restrict__ A, int lda,
                  const TB* __restrict__ B,
                  const float* __restrict__ bias,
                  TO* __restrict__ C, int ldc,
                  int M, int N, int K)
{
    __shared__ bf16 sA[BM * BK];
    __shared__ bf16 sB[BN * BK];
    const int tid  = threadIdx.x;
    const int wave = tid >> 6, lane = tid & 63;
    const int quad = lane >> 4, l16 = lane & 15;
    const int wm = wave >> 1, wn = wave & 1;
    const int rowBase = blockIdx.x * BM;
    const int colBase = blockIdx.y * BN;

    int c0 = wave * 128 + lane;
    int rowA0 = c0 >> 2, kgA0 = c0 & 3;
    int rowA1 = (c0 + 64) >> 2, kgA1 = (c0 + 64) & 3;

    f32x4 acc[4][4] = {};

    for (int k0 = 0; k0 < K; k0 += BK) {
        bf16x8 ra0 = load8(A + (size_t)(rowBase + rowA0) * lda + k0 + kgA0 * 8);
        bf16x8 ra1 = load8(A + (size_t)(rowBase + rowA1) * lda + k0 + kgA1 * 8);
        bf16x8 rb0 = load8(B + (size_t)(colBase + rowA0) * K + k0 + kgA0 * 8);
        bf16x8 rb1 = load8(B + (size_t)(colBase + rowA1) * K + k0 + kgA1 * 8);
        __syncthreads();
        *(bf16x8*)(sA + rowA0 * BK + kgA0 * 8) = ra0;
        *(bf16x8*)(sA + rowA1 * BK + kgA1 * 8) = ra1;
        *(bf16x8*)(sB + rowA0 * BK + kgA0 * 8) = rb0;
        *(bf16x8*)(sB + rowA1 * BK + kgA1 * 8) = rb1;
        __syncthreads();

        bf16x8 af[4], bfr[4];
        for (int mi = 0; mi < 4; ++mi)
            af[mi] = *(const bf16x8*)(sA + (wm * 64 + mi * 16 + l16) * BK + quad * 8);
        for (int ni = 0; ni < 4; ++ni)
            bfr[ni] = *(const bf16x8*)(sB + (wn * 64 + ni * 16 + l16) * BK + quad * 8);
        for (int mi = 0; mi < 4; ++mi)
            for (int ni = 0; ni < 4; ++ni)
                acc[mi][ni] = __builtin_amdgcn_mfma_f32_16x16x32_bf16(
                    af[mi], bfr[ni], acc[mi][ni], 0, 0, 0);
    }

    for (int ni = 0; ni < 4; ++ni) {
        int col = colBase + wn * 64 + ni * 16 + l16;
        float bv = bias ? bias[col] : 0.0f;
        for (int mi = 0; mi < 4; ++mi) {
            int row0 = rowBase + wm * 64 + mi * 16 + quad * 4;
            for (int r = 0; r < 4; ++r)
                C[(size_t)(row0 + r) * ldc + col] = (TO)(acc[mi][ni][r] + bv);
        }
    }
}

// ---------------- RMSNorm (over full 4096) + RoPE, IN PLACE ----------------
// Round 6: only 64 distinct RoPE angles exist per row (ang depends on d=i&63,
// not h) -- was computed 2048x/block.  Now: 64-entry LDS sincos table
// (bit-identical: same sincosf on same inputs) + bf16x8-vectorized rope loop
// (was scalar 2-B loads).  Exact coverage: thread -> (h=tid>>3, d0=(tid&7)*8).
__global__ __launch_bounds__(256)
void rmsnorm_rope(bf16* __restrict__ qkv, const float* __restrict__ qw,
                  const float* __restrict__ kw, const int* __restrict__ pos)
{
    const int t   = blockIdx.x;
    const int sel = blockIdx.y;
    bf16* x = qkv + (size_t)t * QKV_N + sel * 4096;
    const float* w = sel ? kw : qw;
    const int tid = threadIdx.x;

    __shared__ float red[4];
    __shared__ float csv[64];
    __shared__ float snv[64];

    float ss = 0.f;
    {
        int i0 = tid * 16;
        bf16x8 a = *(const bf16x8*)(x + i0);
        bf16x8 b = *(const bf16x8*)(x + i0 + 8);
#pragma unroll
        for (int j = 0; j < 8; ++j) { float fa = (float)a[j]; ss += fa * fa; }
#pragma unroll
        for (int j = 0; j < 8; ++j) { float fb = (float)b[j]; ss += fb * fb; }
    }
    for (int off = 1; off < 64; off <<= 1) ss += __shfl_xor(ss, off, 64);
    if ((tid & 63) == 0) red[tid >> 6] = ss;
    if (tid < 64) {
        float fp  = (float)pos[t];
        float ang = fp * exp2f(-(float)tid * 0.31143075889569023f);
        float s, c;
        sincosf(ang, &s, &c);
        csv[tid] = c; snv[tid] = s;
    }
    __syncthreads();
    float tot  = red[0] + red[1] + red[2] + red[3];
    float rstd = rsqrtf(tot * (1.0f / 4096.0f) + 1e-5f);

    const int h  = tid >> 3;
    const int d0 = (tid & 7) * 8;
    const int base = h * 128 + d0;
    bf16x8 v1 = *(const bf16x8*)(x + base);
    bf16x8 v2 = *(const bf16x8*)(x + base + 64);
    bf16x8 o1, o2;
#pragma unroll
    for (int j = 0; j < 8; ++j) {
        float x1 = (float)v1[j] * rstd * w[base + j];
        float x2 = (float)v2[j] * rstd * w[base + 64 + j];
        float c = csv[d0 + j], s = snv[d0 + j];
        o1[j] = (bf16)(x1 * c - x2 * s);
        o2[j] = (bf16)(x2 * c + x1 * s);
    }
    *(bf16x8*)(x + base)      = o1;
    *(bf16x8*)(x + base + 64) = o2;
}

// ---------------- V transpose (vectorized global, 16 B both sides) ---------
// Round 6: was scalar 2-B global reads AND writes.  Now bf16x8 global on
// both sides; transpose via LDS tile[d][t] with row stride 65 (bank-verified:
// phase-1 scalar writes lane-stride 16*65 B -> bank step 4, <=2 lanes/bank
// = free; phase-2 scalar reads likewise <=2-way).  BW-bound (~33 MB moved).
__global__ __launch_bounds__(256)
void v_transpose(const bf16* __restrict__ qkv, bf16* __restrict__ vt)
{
    __shared__ bf16 tile[64 * 65];
    const int t0 = blockIdx.x * 64, d0 = blockIdx.y * 64, h = blockIdx.z;
    const int tid = threadIdx.x;

#pragma unroll
    for (int c = tid; c < 512; c += 256) {
        int t = c >> 3, dc = (c & 7) * 8;
        bf16x8 v = *(const bf16x8*)(qkv + (size_t)(t0 + t) * QKV_N + V_OFF +
                                    h * HD + d0 + dc);
#pragma unroll
        for (int j = 0; j < 8; ++j) tile[(dc + j) * 65 + t] = v[j];
    }
    __syncthreads();
#pragma unroll
    for (int c = tid; c < 512; c += 256) {
        int d = c >> 3, tc = (c & 7) * 8;
        bf16x8 o;
#pragma unroll
        for (int j = 0; j < 8; ++j) o[j] = tile[d * 65 + tc + j];
        *(bf16x8*)(vt + (size_t)(h * HD + d0 + d) * T_SEQ + t0 + tc) = o;
    }
}

// ---------------- Flash attention (causal) ---------------------------------
#define SKP 136
#define SVP 72
#define PBP 72

__global__ __launch_bounds__(256, 2)
void flash_attn(bf16* qkv, const bf16* vt)
{
    __shared__ bf16 sK[64 * SKP];
    __shared__ bf16 sV[128 * SVP];
    __shared__ bf16 pbuf[4 * 16 * PBP];

    const int tid  = threadIdx.x;
    const int wave = tid >> 6, lane = tid & 63;
    const int quad = lane >> 4, l16 = lane & 15;
    const int h    = blockIdx.y;

    const float sc = 0.08838834764831845f * 1.4426950408889634f;  // scale*log2e
    bf16* pb = pbuf + wave * 16 * PBP;

    for (int half = 0; half < 2; ++half) {
        const int blk  = half ? (31 - (int)blockIdx.x) : (int)blockIdx.x;
        const int q0w  = blk * 64 + wave * 16;
        const int kend = blk * 64;
        const int qln  = q0w + l16;

        bf16x8 qf[4];
        {
            const bf16* qrow = qkv + (size_t)qln * QKV_N + h * HD;
            for (int c = 0; c < 4; ++c)
                qf[c] = *(const bf16x8*)(qrow + c * 32 + quad * 8);
        }

        f32x4 oacc[8] = {};
        float m2 = -1e30f, lsum = 0.f;

        for (int kb = 0; kb <= kend; kb += 64) {
            __syncthreads();
            for (int j = 0; j < 4; ++j) {
                int c = tid + j * 256;
                int r = c >> 4, off = (c & 15) * 8;
                bf16x8 v = *(const bf16x8*)(qkv + (size_t)(kb + r) * QKV_N + 4096 + h * HD + off);
                *(bf16x8*)(sK + r * SKP + off) = v;
            }
            for (int j = 0; j < 4; ++j) {
                int c = tid + j * 256;
                int d = c >> 3, off = (c & 7) * 8;
                bf16x8 v = *(const bf16x8*)(vt + (size_t)(h * HD + d) * T_SEQ + kb + off);
                *(bf16x8*)(sV + d * SVP + off) = v;
            }
            __syncthreads();

            const int stmax = (kb == kend) ? (wave + 1) : 4;

            f32x4 s[4] = {};
            for (int st = 0; st < 4; ++st) {
                if (st >= stmax) break;
                const bf16* kbase = sK + (st * 16 + l16) * SKP + quad * 8;
                for (int c = 0; c < 4; ++c) {
                    bf16x8 kf = *(const bf16x8*)(kbase + c * 32);
                    s[st] = __builtin_amdgcn_mfma_f32_16x16x32_bf16(kf, qf[c], s[st], 0, 0, 0);
                }
            }
            for (int st = 0; st < 4; ++st) {
                int k0r = kb + st * 16 + quad * 4;
                for (int r = 0; r < 4; ++r) {
                    float v = s[st][r] * sc;
                    s[st][r] = (k0r + r <= qln) ? v : -1e30f;
                }
            }
            float mx = -1e30f;
            for (int st = 0; st < 4; ++st)
                for (int r = 0; r < 4; ++r) mx = fmaxf(mx, s[st][r]);
            mx = fmaxf(mx, __shfl_xor(mx, 16, 64));
            mx = fmaxf(mx, __shfl_xor(mx, 32, 64));
            float mnew  = fmaxf(m2, mx);
            float alpha = exp2f(m2 - mnew);
            float ps = 0.f;
            for (int st = 0; st < 4; ++st)
                for (int r = 0; r < 4; ++r) {
                    float p = exp2f(s[st][r] - mnew);
                    s[st][r] = p;
                    ps += p;
                }
            ps += __shfl_xor(ps, 16, 64);
            ps += __shfl_xor(ps, 32, 64);
            lsum = lsum * alpha + ps;
            m2 = mnew;

            float ar[4];
            for (int r = 0; r < 4; ++r) ar[r] = __shfl(alpha, quad * 4 + r, 64);
            for (int c = 0; c < 8; ++c)
                for (int r = 0; r < 4; ++r) oacc[c][r] *= ar[r];

            for (int st = 0; st < 4; ++st) {
                bf16x4 pw;
                for (int r = 0; r < 4; ++r) pw[r] = (bf16)s[st][r];
                *(bf16x4*)(pb + l16 * PBP + st * 16 + quad * 4) = pw;
            }
            __builtin_amdgcn_s_waitcnt(0xC07F);  // lgkmcnt(0)
            for (int ph = 0; ph < 2; ++ph) {
                bf16x8 pf = *(const bf16x8*)(pb + l16 * PBP + ph * 32 + quad * 8);
                for (int c = 0; c < 8; ++c) {
                    bf16x8 vf = *(const bf16x8*)(sV + (c * 16 + l16) * SVP + ph * 32 + quad * 8);
                    oacc[c] = __builtin_amdgcn_mfma_f32_16x16x32_bf16(pf, vf, oacc[c], 0, 0, 0);
                }
            }
        }

        float lr[4];
        for (int r = 0; r < 4; ++r) lr[r] = __shfl(lsum, quad * 4 + r, 64);
        for (int r = 0; r < 4; ++r) {
            float inv = 1.0f / lr[r];
            int t = q0w + quad * 4 + r;
            for (int c = 0; c < 8; ++c)
                qkv[(size_t)t * QKV_N + V_OFF + h * HD + c * 16 + l16] =
                    (bf16)(oacc[c][r] * inv);
        }
    }
}

extern "C" void kernel_launch(void* const* d_in, const int* in_sizes, int n_in,
                              void* d_out, int out_size, void* d_ws, size_t ws_size,
                              hipStream_t stream)
{
    const float* hidden   = (const float*)d_in[0];
    const int*   pos      = (const int*)d_in[1];
    const float* w_qkv    = (const float*)d_in[2];
    const float* b_qkv    = (const float*)d_in[3];
    const float* q_norm_w = (const float*)d_in[4];
    const float* k_norm_w = (const float*)d_in[5];
    const float* w_o      = (const float*)d_in[6];
    float* out = (float*)d_out;

    bf16* qkv = (bf16*)d_ws;                         //  50.33 MB
    bf16* vt  = qkv + (size_t)T_SEQ * QKV_N;         //  16.78 MB
    bf16* wqb = vt  + (size_t)4096 * T_SEQ;          // 100.66 MB
    bf16* wob = wqb + (size_t)QKV_N * 4096;          //  33.55 MB
    bf16* hib = wob + (size_t)4096 * 4096;           //  16.78 MB
    const size_t need = ((size_t)T_SEQ * QKV_N + (size_t)4096 * T_SEQ +
                         (size_t)QKV_N * 4096 + (size_t)4096 * 4096 +
                         (size_t)T_SEQ * 4096) * 2;

    if (ws_size >= need) {
        f32_to_bf16<<<2048, 256, 0, stream>>>(hidden, hib, T_SEQ * 4096 / 8);
        f32_to_bf16<<<8192, 256, 0, stream>>>(w_qkv, wqb, QKV_N * 4096 / 8);
        f32_to_bf16<<<4096, 256, 0, stream>>>(w_o, wob, 4096 * 4096 / 8);

        // QKV GEMM: 2048x12288x4096; 256x128 tiles -> 8x96 = 768 blocks (3 rounds)
        gemm_bt_p1<bf16><<<768, 512, 0, stream>>>(
            hib, 4096, wqb, b_qkv, qkv, QKV_N, 8, 12, 4096);
        rmsnorm_rope<<<dim3(T_SEQ, 2), 256, 0, stream>>>(qkv, q_norm_w, k_norm_w, pos);
        v_transpose<<<dim3(T_SEQ / 64, 2, NH), 256, 0, stream>>>(qkv, vt);
        flash_attn<<<dim3(T_SEQ / 128, NH), 256, 0, stream>>>(qkv, vt);
        // O GEMM: 2048x4096x4096; 256x128 tiles -> 8x32 = 256 blocks (1 round)
        gemm_bt_p1<float><<<256, 512, 0, stream>>>(
            qkv + V_OFF, QKV_N, wob, nullptr, out, 4096, 8, 4, 4096);
    } else {
        gemm_bt_bias<float, float, bf16><<<dim3(T_SEQ / BM, QKV_N / BN), 256, 0, stream>>>(
            hidden, 4096, w_qkv, b_qkv, qkv, QKV_N, T_SEQ, QKV_N, 4096);
        rmsnorm_rope<<<dim3(T_SEQ, 2), 256, 0, stream>>>(qkv, q_norm_w, k_norm_w, pos);
        v_transpose<<<dim3(T_SEQ / 64, 2, NH), 256, 0, stream>>>(qkv, vt);
        flash_attn<<<dim3(T_SEQ / 128, NH), 256, 0, stream>>>(qkv, vt);
        gemm_bt_bias<bf16, float, float><<<dim3(T_SEQ / BM, 4096 / BN), 256, 0, stream>>>(
            qkv + V_OFF, QKV_N, w_o, nullptr, out, 4096, T_SEQ, 4096, 4096);
    }
}